// Round 1
// baseline (78.201 us; speedup 1.0000x reference)
//
#include <hip/hip_runtime.h>

// GLCM layer: quantize to 8 levels, 8 angle shifts, co-occurrence code,
// 5x5 reflect box filter over 64 one-hot channels, 32x32 avg pool.
//
// R3: block = (b, py, px, row-strip), ALL 8 angles per block.
//     - staging/quantization redundancy drops 8x -> 1.33x (halo only)
//     - weight product + g1 read amortized over 8 angles
//     - per-wave privatized 512-bin (8 angle x 64 code) LDS histograms
//     - cross-strip accumulation via exact global f32 atomics
//       (all contributions are integer * 2^-10 -> order-independent, exact)

#define POOLSZ 32
#define H      256
#define W      256
#define NLEV   8
#define NCODE  64
#define NANG   8
#define SR     6            // pixel rows per strip
#define NSTRIP 6            // SR * NSTRIP = 36 pixel rows
#define SROWS  (SR + 2)     // staged rows (pixel rows + gl2 halo)
#define TW     38           // staged cols = 32 + 2*boxpad + 2*anglehalo
#define NWAVE  4

__device__ __forceinline__ int reflect_idx(int t) {
    if (t < 0)   return -t;
    if (t > 255) return 510 - t;
    return t;
}

__global__ __launch_bounds__(256) void glcm_kernel(const float* __restrict__ x,
                                                   float* __restrict__ out) {
    const int s  = blockIdx.x;          // strip index 0..5
    const int px = blockIdx.y & 7;
    const int py = blockIdx.y >> 3;
    const int b  = blockIdx.z;

    __shared__ int   gl[SROWS][TW];     // quantized strip tile (int: bank-friendly)
    __shared__ float wrowS[SROWS];
    __shared__ float wcol[TW];
    __shared__ float hist4[NWAVE * NANG * NCODE];   // 4 x 512 privatized bins

    const int tid = threadIdx.x;
    const int wid = tid >> 6;

    // global row of staged local row 0 for this strip; col of staged col 0
    const int row0 = py * POOLSZ - 3 + s * SR;
    const int col0 = px * POOLSZ - 3;

    for (int i = tid; i < NWAVE * NANG * NCODE; i += 256) hist4[i] = 0.0f;

    if (wid < 3) {
        // Waves 0-2 (192 threads): stage + quantize the strip tile.
        const float* xb = x + b * (H * W);
        for (int i = tid; i < SROWS * TW; i += 192) {
            int ly = i / TW, lx = i % TW;
            int gy = min(max(row0 + ly, 0), H - 1);
            int gx = min(max(col0 + lx, 0), W - 1);
            float v = xb[gy * W + gx];
            // searchsorted(linspace(0,256,9), v, 'left')-1 == ceil(v/32)-1 (v=0 -> -1)
            gl[ly][lx] = (int)ceilf(v * 0.03125f) - 1;
        }
    } else {
        // Wave 3: 1-D box+pool overlap weights (cols 0..37, then strip rows 0..7).
        for (int j = tid - 192; j < TW + SROWS; j += 64) {
            int dim = (j >= TW);                 // 0 = col, 1 = row
            int l   = dim ? (j - TW) : j;
            int o   = dim ? row0 : col0;
            int p   = dim ? py : px;
            int lo  = p * POOLSZ, hi = lo + POOLSZ - 1;
            int s_abs = o + l;
            int wgt = 0;
            if (s_abs >= 0 && s_abs <= 255) {
                for (int t = lo - 2; t <= hi + 2; ++t) {
                    if (reflect_idx(t) == s_abs)
                        wgt += min(t + 2, hi) - max(t - 2, lo) + 1;
                }
            }
            if (dim) wrowS[l] = (float)wgt; else wcol[l] = (float)wgt;
        }
    }
    __syncthreads();

    // angle -> (offy, offx): gl2[y][x] = gl1[clamp(y+offy)][clamp(x+offx)]
    const int offy_t[8] = {0, -1, -1, -1, 0, 1, 1, 1};
    const int offx_t[8] = {1,  1,  0, -1, -1, -1, 0, 1};

    float* myh = &hist4[wid * (NANG * NCODE)];
    for (int i = tid; i < SR * 36; i += 256) {
        int ly = i / 36 + 1;                     // staged-local pixel row 1..SR
        int lx = i % 36 + 1;                     // staged-local pixel col 1..36
        float w = wrowS[ly] * wcol[lx];
        if (w == 0.0f) continue;
        int g1   = gl[ly][lx];
        int base = g1 * NLEV;                    // may be negative (v==0) -> code<0 skip
        #pragma unroll
        for (int a = 0; a < NANG; ++a) {
            int g2   = gl[ly + offy_t[a]][lx + offx_t[a]];
            int code = base + g2;                // in [-9, 63]
            if (code >= 0) atomicAdd(&myh[a * NCODE + code], w);
        }
    }
    __syncthreads();

    // Reduce the 4 wave histograms, accumulate into out with exact f32 atomics.
    // out[((b*512 + a*64 + c) * 64) + py*8 + px], k = a*64+c
    for (int k = tid; k < NANG * NCODE; k += 256) {
        float v = hist4[k] + hist4[512 + k] + hist4[1024 + k] + hist4[1536 + k];
        if (v != 0.0f)
            atomicAdd(&out[(size_t)(b * 512 + k) * 64 + py * 8 + px],
                      v * (1.0f / 1024.0f));
    }
}

extern "C" void kernel_launch(void* const* d_in, const int* in_sizes, int n_in,
                              void* d_out, int out_size, void* d_ws, size_t ws_size,
                              hipStream_t stream) {
    const float* x = (const float*)d_in[0];
    float* out = (float*)d_out;
    hipMemsetAsync(d_out, 0, (size_t)out_size, stream);
    glcm_kernel<<<dim3(NSTRIP, 64, 2), dim3(256), 0, stream>>>(x, out);
}

// Round 2
// 61.853 us; speedup vs baseline: 1.2643x; 1.2643x over previous
//
#include <hip/hip_runtime.h>

// GLCM layer: quantize to 8 levels, 8 angle shifts, co-occurrence code,
// 5x5 reflect box filter over 64 one-hot channels, 32x32 avg pool.
// Fused: pooled output = weighted histogram over a 36x36 source window.
//
// R4: block = (b, py, px, angle-PAIR). One dispatch, direct stores (no memset,
//     no global atomics — R3's extra graph node cost ~16us). Tile staging and
//     weight-product/g1-read amortized over 2 angles; per-wave privatized
//     2x64-bin LDS histograms keep cross-wave atomic contention at zero.

#define POOLSZ 32
#define H      256
#define W      256
#define NLEV   8
#define NCODE  64
#define NANG   8
#define TILE   38       // 32 + 2*boxpad + 2*angle-halo
#define NWAVE  4

__device__ __forceinline__ int reflect_idx(int t) {
    if (t < 0)   return -t;
    if (t > 255) return 510 - t;
    return t;
}

__global__ __launch_bounds__(256) void glcm_kernel(const float* __restrict__ x,
                                                   float* __restrict__ out) {
    // blockIdx.x = ((b*8 + py)*8 + px)*4 + ap   (ap = angle pair 0..3)
    const int bid = blockIdx.x;
    const int ap  = bid & 3;
    const int px  = (bid >> 2) & 7;
    const int py  = (bid >> 5) & 7;
    const int b   = bid >> 8;

    __shared__ signed char gl[TILE][TILE];
    __shared__ float wrow[TILE];
    __shared__ float wcol[TILE];
    __shared__ float hist4[NWAVE * 2 * NCODE];   // 4 waves x 2 angles x 64 bins

    const int tid = threadIdx.x;
    const int wid = tid >> 6;

    // zero the privatized histograms (512 floats / 256 threads = 2 each)
    hist4[tid]       = 0.0f;
    hist4[tid + 256] = 0.0f;

    const int row0 = py * POOLSZ - 3;        // tile origin (pool block start - halo)
    const int col0 = px * POOLSZ - 3;

    if (wid < 3) {
        // Waves 0-2 (192 threads): stage quantized tile, global-clamped halo.
        const float* xb = x + b * (H * W);
        for (int i = tid; i < TILE * TILE; i += 192) {
            int ly = i / TILE, lx = i % TILE;
            int gy = min(max(row0 + ly, 0), H - 1);
            int gx = min(max(col0 + lx, 0), W - 1);
            float v = xb[gy * W + gx];
            // searchsorted(linspace(0,256,9), v, 'left')-1 == ceil(v/32)-1 (v=0 -> -1)
            gl[ly][lx] = (signed char)((int)ceilf(v * 0.03125f) - 1);
        }
    } else {
        // Wave 3: 1-D box+pool overlap weights.
        for (int j = tid - 192; j < 2 * TILE; j += 64) {
            int dim = j / TILE;              // 0 = row, 1 = col
            int l   = j % TILE;
            int o   = dim ? col0 : row0;
            int p   = dim ? px : py;
            int lo  = p * POOLSZ, hi = lo + POOLSZ - 1;
            int s_abs = o + l;
            int wgt = 0;
            if (s_abs >= 0 && s_abs <= 255) {
                for (int t = lo - 2; t <= hi + 2; ++t) {
                    if (reflect_idx(t) == s_abs)
                        wgt += min(t + 2, hi) - max(t - 2, lo) + 1;
                }
            }
            if (dim) wcol[l] = (float)wgt; else wrow[l] = (float)wgt;
        }
    }
    __syncthreads();

    // angle -> (offy, offx): gl2[y][x] = gl1[clamp(y+offy)][clamp(x+offx)]
    const int offy_t[8] = {0, -1, -1, -1, 0, 1, 1, 1};
    const int offx_t[8] = {1,  1,  0, -1, -1, -1, 0, 1};
    const int a0  = ap * 2;
    const int oy0 = offy_t[a0],     ox0 = offx_t[a0];
    const int oy1 = offy_t[a0 + 1], ox1 = offx_t[a0 + 1];

    float* myh = &hist4[wid * (2 * NCODE)];
    for (int i = tid; i < 36 * 36; i += 256) {
        int ly = i / 36 + 1;
        int lx = i % 36 + 1;
        float w = wrow[ly] * wcol[lx];
        if (w == 0.0f) continue;
        int base = gl[ly][lx] * NLEV;        // negative (v==0) -> codes stay negative
        int c0 = base + gl[ly + oy0][lx + ox0];
        int c1 = base + gl[ly + oy1][lx + ox1];
        if (c0 >= 0) atomicAdd(&myh[c0], w);
        if (c1 >= 0) atomicAdd(&myh[NCODE + c1], w);
    }
    __syncthreads();

    // Reduce 4 wave copies, direct store (block owns its 128 output channels).
    // out[((b*512 + a*64 + k) * 64) + py*8 + px]
    if (tid < 2 * NCODE) {
        float s = hist4[tid] + hist4[2 * NCODE + tid] + hist4[4 * NCODE + tid]
                + hist4[6 * NCODE + tid];
        int a = a0 + (tid >> 6);             // which angle of the pair
        int k = tid & 63;                    // code bin
        out[((size_t)(b * (NANG * NCODE) + a * NCODE + k) * 64) + py * 8 + px]
            = s * (1.0f / 1024.0f);
    }
}

extern "C" void kernel_launch(void* const* d_in, const int* in_sizes, int n_in,
                              void* d_out, int out_size, void* d_ws, size_t ws_size,
                              hipStream_t stream) {
    const float* x = (const float*)d_in[0];
    float* out = (float*)d_out;
    glcm_kernel<<<dim3(2 * 8 * 8 * 4), dim3(256), 0, stream>>>(x, out);
}